// Round 8
// baseline (3051.134 us; speedup 1.0000x reference)
//
#include <hip/hip_runtime.h>
#include <stdint.h>
#include <stddef.h>

#define Bsz 1024
#define Tsz 512
#define Dsz 256
#define Hsz 256
#define SLAB 24576   // bytes per (t, bgroup16) slab: [r 8K][n 8K][a 8K]; tile ct: +ct*512

typedef __bf16 bf16;
typedef __attribute__((ext_vector_type(8))) __bf16 bf16x8;
typedef __attribute__((ext_vector_type(4))) float f32x4;

#define MFMA __builtin_amdgcn_mfma_f32_16x16x32_bf16

__device__ __forceinline__ float sigm(float x) {
  return __builtin_amdgcn_rcpf(1.f + exp2f(-1.4426950408889634f * x));
}
__device__ __forceinline__ float bflo(uint32_t v) {
  union { uint32_t u; float f; } c; c.u = v << 16; return c.f;
}
__device__ __forceinline__ float bfhi(uint32_t v) {
  union { uint32_t u; float f; } c; c.u = v & 0xffff0000u; return c.f;
}

// ============ repack Wx(R,N), Wh(R,N) into MFMA-fragment-major bf16 ============
// frag f=(tile,kp): elem at lane(lq,lr),e  =  W[tile*16+lr][kp*32+lq*8+e]
__global__ __launch_bounds__(256) void k_repack(
    const float* __restrict__ Wx, const float* __restrict__ Wh,
    bf16* __restrict__ wxf, bf16* __restrict__ whf) {
  int g = blockIdx.x * 256 + threadIdx.x;   // 32768 total
  int gg = g & 16383;
  int lr = gg & 15, lq = (gg >> 4) & 3, kp = (gg >> 6) & 7, tile = gg >> 9;
  int row = (tile < 16) ? (tile * 16 + lr) : (512 + (tile - 16) * 16 + lr);
  const float* s;
  bf16* d;
  if (g < 16384) { s = Wx + row * 256 + kp * 32 + lq * 8; d = wxf + gg * 8; }
  else           { s = Wh + row * 256 + kp * 32 + lq * 8; d = whf + gg * 8; }
  #pragma unroll
  for (int e = 0; e < 8; ++e) d[e] = (bf16)s[e];
}

// ==== Wc = Wa_h @ Wh_I ; Wp = Wa_i @ Wx_I ; c0 = ba + Wa_h@bh_I + Wa_i@bx_I ====
__global__ __launch_bounds__(256) void k_wc(
    const float* __restrict__ Wa, const float* __restrict__ Wh,
    const float* __restrict__ Wx, const float* __restrict__ bh,
    const float* __restrict__ bx, const float* __restrict__ ba,
    bf16* __restrict__ wcf, bf16* __restrict__ wxf, float* __restrict__ c0) {
  __shared__ float red[256];
  int n = blockIdx.x, k = threadIdx.x;
  float accC = 0.f, accP = 0.f;
  for (int m = 0; m < 256; ++m) {
    accC += Wa[n * 512 + 256 + m] * Wh[(256 + m) * 256 + k];
    accP += Wa[n * 512 + m]       * Wx[(256 + m) * 256 + k];
  }
  int kp = k >> 5, lq = (k >> 3) & 3, e = k & 7;
  int ti = n >> 4, lr = n & 15;
  wcf[(ti * 8 + kp) * 512 + lq * 128 + lr * 8 + e] = (bf16)accC;
  wxf[(((32 + ti) * 8) + kp) * 512 + lq * 128 + lr * 8 + e] = (bf16)accP;
  red[k] = Wa[n * 512 + 256 + k] * bh[256 + k] + Wa[n * 512 + k] * bx[256 + k];
  __syncthreads();
  for (int s = 128; s > 0; s >>= 1) {
    if (k < s) red[k] += red[k + s];
    __syncthreads();
  }
  if (k == 0) c0[n] = ba[n] + red[0];
}

// ============ phase 1: weight-RESIDENT gx precompute, 1 wave/SIMD ============
// 256 thr / 4 waves; wave w owns flat col-tiles [12w, 12w+12) of {R16|N16|A16}.
// Biases folded: r-region bx+bh_r (gate-linear), n-region bx only (bh_n is
// scaled by resetgate -> must stay in phase2!), a-region c0.
__global__ __launch_bounds__(256) __attribute__((amdgpu_waves_per_eu(1, 1)))
void k_phase1(
    const float* __restrict__ x, const bf16* __restrict__ wxf,
    const float* __restrict__ bx, const float* __restrict__ bh,
    const float* __restrict__ c0, bf16* __restrict__ gx, int t0, int TP) {
  int tid = threadIdx.x;
  int w = tid >> 6, l = tid & 63, lr = l & 15, lq = l >> 4;
  int bg = blockIdx.x, b0 = bg << 4;
  int tl0 = blockIdx.y * TP;
  int loffE = lq * 128 + lr * 8;

  bf16x8 W[12][8];     // 384 VGPRs, resident (1 wave/SIMD -> 512-reg budget)
  float bias[12];
  #pragma unroll
  for (int i = 0; i < 12; ++i) {
    int ft = w * 12 + i;
    #pragma unroll
    for (int kk = 0; kk < 8; ++kk)
      W[i][kk] = *(const bf16x8*)(wxf + (size_t)(ft * 8 + kk) * 512 + loffE);
    int rgn = ft >> 4, r = (ft & 15) * 16 + lr;
    bias[i] = (rgn == 0) ? bx[r] + bh[r]
            : (rgn == 1) ? bx[512 + r]          // NO bh_n here (reset-gated)
            : c0[r];
  }
  const float* xbase = x + (size_t)(b0 + lr) * (Tsz * Dsz) + lq * 8;
  #pragma unroll 1
  for (int tt = 0; tt < TP; ++tt) {
    int tloc = tl0 + tt;
    const float* xp = xbase + (size_t)(t0 + tloc) * Dsz;
    bf16x8 A[8];
    #pragma unroll
    for (int kk = 0; kk < 8; ++kk) {
      float4 f0 = *(const float4*)(xp + kk * 32);
      float4 f1 = *(const float4*)(xp + kk * 32 + 4);
      bf16x8 a;
      a[0] = (bf16)f0.x; a[1] = (bf16)f0.y; a[2] = (bf16)f0.z; a[3] = (bf16)f0.w;
      a[4] = (bf16)f1.x; a[5] = (bf16)f1.y; a[6] = (bf16)f1.z; a[7] = (bf16)f1.w;
      A[kk] = a;
    }
    char* sb = (char*)gx + ((size_t)tloc * 64 + bg) * SLAB;
    #pragma unroll
    for (int g = 0; g < 4; ++g) {    // 3 tiles per group keeps acc small
      f32x4 acc[3];
      #pragma unroll
      for (int i2 = 0; i2 < 3; ++i2)
        #pragma unroll
        for (int e = 0; e < 4; ++e) acc[i2][e] = bias[g * 3 + i2];
      #pragma unroll
      for (int kk = 0; kk < 8; ++kk)
        #pragma unroll
        for (int i2 = 0; i2 < 3; ++i2)
          acc[i2] = MFMA(A[kk], W[g * 3 + i2][kk], acc[i2], 0, 0, 0);
      #pragma unroll
      for (int i2 = 0; i2 < 3; ++i2) {
        int ft = w * 12 + g * 3 + i2;
        union { bf16 v[4]; uint2 u; } pk;
        #pragma unroll
        for (int j = 0; j < 4; ++j) pk.v[j] = (bf16)acc[i2][j];
        *(uint2*)(sb + (ft >> 4) * 8192 + (ft & 15) * 512 + loffE) = pk.u;
      }
    }
  }
}

// ============ phase 2: scan; 4 waves x 64 cols; weights register-resident ============
// 1 wave/SIMD (512-reg budget): 96 frags = 384 regs + ~100 working. Zero weight stream.
__global__ __launch_bounds__(256) __attribute__((amdgpu_waves_per_eu(1, 1)))
void k_phase2(
    const bf16* __restrict__ gx, const bf16* __restrict__ whf,
    const bf16* __restrict__ wcf, const float* __restrict__ bh,
    float* __restrict__ out, float* __restrict__ hstate, int t0, int TC) {
  __shared__ char hb[2][8192];   // h bf16 A-frag layout, double-buffered
  int tid = threadIdx.x;
  int w = tid >> 6, l = tid & 63, lr = l & 15, lq = l >> 4;
  int bg = blockIdx.x, b0 = bg << 4;
  int loffE = lq * 128 + lr * 8;

  bf16x8 wR[4][8], wN[4][8], wC[4][8];   // 384 VGPRs
  #pragma unroll
  for (int g = 0; g < 4; ++g)
    #pragma unroll
    for (int kk = 0; kk < 8; ++kk) {
      int ct = 4 * w + g;
      wR[g][kk] = *(const bf16x8*)(whf + (size_t)(ct * 8 + kk) * 512 + loffE);
      wN[g][kk] = *(const bf16x8*)(whf + (size_t)((16 + ct) * 8 + kk) * 512 + loffE);
      wC[g][kk] = *(const bf16x8*)(wcf + (size_t)(ct * 8 + kk) * 512 + loffE);
    }
  float bN[4];   // bh_n seed for accN (reset-gated, cannot be pre-folded)
  #pragma unroll
  for (int g = 0; g < 4; ++g) bN[g] = bh[512 + (4 * w + g) * 16 + lr];

  float h[4][4];   // [group][row j]
  #pragma unroll
  for (int g = 0; g < 4; ++g) {
    int col = (4 * w + g) * 16 + lr;
    #pragma unroll
    for (int j = 0; j < 4; ++j)
      h[g][j] = (t0 == 0) ? 0.f : hstate[(size_t)(b0 + 4 * lq + j) * Hsz + col];
    int cb = ((col >> 5) << 10) + (((col >> 3) & 3) << 8) + (lq << 6) + ((col & 7) << 1);
    char* hw = hb[0] + cb;
    #pragma unroll
    for (int j = 0; j < 4; ++j) *(bf16*)(hw + j * 16) = (bf16)h[g][j];
  }
  __syncthreads();

  const char* gxb = (const char*)gx + (size_t)bg * SLAB;
  const size_t tstride = (size_t)64 * SLAB;
  uint2 gR[4], gN[4], gA[4];
  #pragma unroll
  for (int g = 0; g < 4; ++g) {
    int toff = (4 * w + g) * 512 + loffE;
    gR[g] = *(const uint2*)(gxb + toff);
    gN[g] = *(const uint2*)(gxb + 8192 + toff);
    gA[g] = *(const uint2*)(gxb + 16384 + toff);
  }

  #pragma unroll 1
  for (int t = 0; t < TC; ++t) {
    int cur = t & 1, nxt = cur ^ 1;
    const char* hc = hb[cur] + lq * 256 + lr * 16;
    bf16x8 Ah[8];
    #pragma unroll
    for (int kk = 0; kk < 8; ++kk) Ah[kk] = *(const bf16x8*)(hc + kk * 1024);
    bool pf = (t + 1 < TC);
    const char* sl = gxb + (size_t)(t + 1) * tstride;
    #pragma unroll
    for (int g = 0; g < 4; ++g) {
      f32x4 aR, aN, aA;
      #pragma unroll
      for (int e = 0; e < 4; ++e) { aR[e] = 0.f; aN[e] = bN[g]; aA[e] = 0.f; }
      #pragma unroll
      for (int kk = 0; kk < 8; ++kk) {
        aR = MFMA(Ah[kk], wR[g][kk], aR, 0, 0, 0);
        aN = MFMA(Ah[kk], wN[g][kk], aN, 0, 0, 0);
        aA = MFMA(Ah[kk], wC[g][kk], aA, 0, 0, 0);
      }
      float irj[4] = { bflo(gR[g].x), bfhi(gR[g].x), bflo(gR[g].y), bfhi(gR[g].y) };
      float inj[4] = { bflo(gN[g].x), bfhi(gN[g].x), bflo(gN[g].y), bfhi(gN[g].y) };
      float aij[4] = { bflo(gA[g].x), bfhi(gA[g].x), bflo(gA[g].y), bfhi(gA[g].y) };
      int col = (4 * w + g) * 16 + lr;
      #pragma unroll
      for (int j = 0; j < 4; ++j) {
        float rg = sigm(irj[j] + aR[j]);
        float xx = inj[j] + rg * aN[j];
        xx = fminf(fmaxf(xx, -15.f), 15.f);
        float e2 = exp2f(-2.885390081777927f * xx);
        float ng = (1.f - e2) * __builtin_amdgcn_rcpf(1.f + e2);
        float ig = sigm(aij[j] + aA[j]);
        h[g][j] = ng + ig * (h[g][j] - ng);
      }
      int cb = ((col >> 5) << 10) + (((col >> 3) & 3) << 8) + (lq << 6) + ((col & 7) << 1);
      char* hw = hb[nxt] + cb;
      #pragma unroll
      for (int j = 0; j < 4; ++j) *(bf16*)(hw + j * 16) = (bf16)h[g][j];
      #pragma unroll
      for (int j = 0; j < 4; ++j)
        out[(size_t)(b0 + 4 * lq + j) * (Tsz * Hsz) + (size_t)(t0 + t) * Hsz + col] = h[g][j];
      if (pf) {   // next step's gx into same regs (WAR after gate reads)
        int toff = (4 * w + g) * 512 + loffE;
        gR[g] = *(const uint2*)(sl + toff);
        gN[g] = *(const uint2*)(sl + 8192 + toff);
        gA[g] = *(const uint2*)(sl + 16384 + toff);
      }
    }
    asm volatile("s_waitcnt lgkmcnt(0)" ::: "memory");
    __builtin_amdgcn_s_barrier();
    __builtin_amdgcn_sched_barrier(0);
  }
  #pragma unroll
  for (int g = 0; g < 4; ++g) {
    int col = (4 * w + g) * 16 + lr;
    #pragma unroll
    for (int j = 0; j < 4; ++j)
      hstate[(size_t)(b0 + 4 * lq + j) * Hsz + col] = h[g][j];
  }
}

extern "C" void kernel_launch(void* const* d_in, const int* in_sizes, int n_in,
                              void* d_out, int out_size, void* d_ws, size_t ws_size,
                              hipStream_t stream) {
  (void)in_sizes; (void)n_in; (void)out_size;
  const float* x  = (const float*)d_in[0];
  const float* Wx = (const float*)d_in[1];
  const float* bx = (const float*)d_in[2];
  const float* Wh = (const float*)d_in[3];
  const float* bh = (const float*)d_in[4];
  const float* Wa = (const float*)d_in[5];
  const float* ba = (const float*)d_in[6];
  float* out = (float*)d_out;
  char* ws = (char*)d_ws;

  bf16* wxf = (bf16*)ws;                        // 48 tiles * 8KB = 393216 B (R,N,Wp)
  bf16* whf = (bf16*)(ws + 393216);             // 262144 B (R tiles 0..15, N tiles 16..31)
  bf16* wcf = (bf16*)(ws + 655360);             // 131072 B
  float* c0 = (float*)(ws + 786432);            // 1024 B
  float* hstate = (float*)(ws + 1048576);       // 1 MB
  bf16* gxbuf = (bf16*)(ws + 2097152);

  size_t avail = (ws_size > 2097152) ? ws_size - 2097152 : 0;
  size_t per_t = (size_t)64 * SLAB;             // 1.5 MB per timestep
  long tcl = (long)(avail / per_t);
  int TC = (tcl > Tsz) ? Tsz : (int)tcl;
  TC &= ~63;
  if (TC < 64) TC = 64;

  k_repack<<<dim3(128), dim3(256), 0, stream>>>(Wx, Wh, wxf, whf);
  k_wc<<<dim3(256), dim3(256), 0, stream>>>(Wa, Wh, Wx, bh, bx, ba, wcf, wxf, c0);
  for (int t0 = 0; t0 < Tsz; t0 += TC) {
    int tc = Tsz - t0; if (tc > TC) tc = TC;
    int TP = (tc % 128 == 0) ? 128 : 64;
    k_phase1<<<dim3(64, tc / TP), dim3(256), 0, stream>>>(x, wxf, bx, bh, c0, gxbuf, t0, TP);
    k_phase2<<<dim3(64), dim3(256), 0, stream>>>(gxbuf, whf, wcf, bh, out, hstate, t0, tc);
  }
}

// Round 10
// 2047.644 us; speedup vs baseline: 1.4901x; 1.4901x over previous
//
#include <hip/hip_runtime.h>
#include <stdint.h>
#include <stddef.h>

#define Bsz 1024
#define Tsz 512
#define Dsz 256
#define Hsz 256
#define SLAB 24576   // bytes per (t, bgroup16) slab: [r 8K][n 8K][a 8K]; tile ct: +ct*512

typedef __bf16 bf16;
typedef __attribute__((ext_vector_type(8))) __bf16 bf16x8;
typedef __attribute__((ext_vector_type(4))) float f32x4;

#define MFMA __builtin_amdgcn_mfma_f32_16x16x32_bf16

__device__ __forceinline__ float sigm(float x) {
  return __builtin_amdgcn_rcpf(1.f + exp2f(-1.4426950408889634f * x));
}
__device__ __forceinline__ float bflo(uint32_t v) {
  union { uint32_t u; float f; } c; c.u = v << 16; return c.f;
}
__device__ __forceinline__ float bfhi(uint32_t v) {
  union { uint32_t u; float f; } c; c.u = v & 0xffff0000u; return c.f;
}
__device__ __forceinline__ bf16x8 asb(uint4 u) {
  union { uint4 a; bf16x8 b; } c; c.a = u; return c.b;
}
// pin: values become asm-defined -> compiler cannot rematerialize their loads.
// NOTE: must tie SCALAR components; 128-bit aggregate ties are unsupported (R9 compile fail).
#define PIN4(v) asm volatile("" : "+v"((v).x), "+v"((v).y), "+v"((v).z), "+v"((v).w))

// ============ repack Wx(R,N), Wh(R,N) into MFMA-fragment-major bf16 ============
// frag f=(tile,kp): elem at lane(lq,lr),e  =  W[tile*16+lr][kp*32+lq*8+e]
__global__ __launch_bounds__(256) void k_repack(
    const float* __restrict__ Wx, const float* __restrict__ Wh,
    bf16* __restrict__ wxf, bf16* __restrict__ whf) {
  int g = blockIdx.x * 256 + threadIdx.x;   // 32768 total
  int gg = g & 16383;
  int lr = gg & 15, lq = (gg >> 4) & 3, kp = (gg >> 6) & 7, tile = gg >> 9;
  int row = (tile < 16) ? (tile * 16 + lr) : (512 + (tile - 16) * 16 + lr);
  const float* s;
  bf16* d;
  if (g < 16384) { s = Wx + row * 256 + kp * 32 + lq * 8; d = wxf + gg * 8; }
  else           { s = Wh + row * 256 + kp * 32 + lq * 8; d = whf + gg * 8; }
  #pragma unroll
  for (int e = 0; e < 8; ++e) d[e] = (bf16)s[e];
}

// ==== Wc = Wa_h @ Wh_I ; Wp = Wa_i @ Wx_I ; c0 = ba + Wa_h@bh_I + Wa_i@bx_I ====
__global__ __launch_bounds__(256) void k_wc(
    const float* __restrict__ Wa, const float* __restrict__ Wh,
    const float* __restrict__ Wx, const float* __restrict__ bh,
    const float* __restrict__ bx, const float* __restrict__ ba,
    bf16* __restrict__ wcf, bf16* __restrict__ wxf, float* __restrict__ c0) {
  __shared__ float red[256];
  int n = blockIdx.x, k = threadIdx.x;
  float accC = 0.f, accP = 0.f;
  for (int m = 0; m < 256; ++m) {
    accC += Wa[n * 512 + 256 + m] * Wh[(256 + m) * 256 + k];
    accP += Wa[n * 512 + m]       * Wx[(256 + m) * 256 + k];
  }
  int kp = k >> 5, lq = (k >> 3) & 3, e = k & 7;
  int ti = n >> 4, lr = n & 15;
  wcf[(ti * 8 + kp) * 512 + lq * 128 + lr * 8 + e] = (bf16)accC;
  wxf[(((32 + ti) * 8) + kp) * 512 + lq * 128 + lr * 8 + e] = (bf16)accP;
  red[k] = Wa[n * 512 + 256 + k] * bh[256 + k] + Wa[n * 512 + k] * bx[256 + k];
  __syncthreads();
  for (int s = 128; s > 0; s >>= 1) {
    if (k < s) red[k] += red[k + s];
    __syncthreads();
  }
  if (k == 0) c0[n] = ba[n] + red[0];
}

// ============ phase 1: weight-resident (pinned) gx precompute ============
// 256 thr / 4 waves, 1 wave/SIMD (512 unified regs); wave w owns tiles [12w,12w+12).
__global__ __launch_bounds__(256) __attribute__((amdgpu_waves_per_eu(1, 1)))
void k_phase1(
    const float* __restrict__ x, const bf16* __restrict__ wxf,
    const float* __restrict__ bx, const float* __restrict__ bh,
    const float* __restrict__ c0, bf16* __restrict__ gx, int t0, int TP) {
  int tid = threadIdx.x;
  int w = tid >> 6, l = tid & 63, lr = l & 15, lq = l >> 4;
  int bg = blockIdx.x, b0 = bg << 4;
  int tl0 = blockIdx.y * TP;
  int loffE = lq * 128 + lr * 8;

  uint4 W[12][8];      // 384 regs, pinned (AGPR overflow handled by allocator)
  float bias[12];
  #pragma unroll
  for (int i = 0; i < 12; ++i) {
    int ft = w * 12 + i;
    #pragma unroll
    for (int kk = 0; kk < 8; ++kk) {
      W[i][kk] = *(const uint4*)(wxf + (size_t)(ft * 8 + kk) * 512 + loffE);
      PIN4(W[i][kk]);
    }
    int rgn = ft >> 4, r = (ft & 15) * 16 + lr;
    bias[i] = (rgn == 0) ? bx[r] + bh[r]
            : (rgn == 1) ? bx[512 + r]          // NO bh_n here (reset-gated)
            : c0[r];
  }
  const float* xbase = x + (size_t)(b0 + lr) * (Tsz * Dsz) + lq * 8;
  #pragma unroll 1
  for (int tt = 0; tt < TP; ++tt) {
    int tloc = tl0 + tt;
    const float* xp = xbase + (size_t)(t0 + tloc) * Dsz;
    bf16x8 A[8];
    #pragma unroll
    for (int kk = 0; kk < 8; ++kk) {
      float4 f0 = *(const float4*)(xp + kk * 32);
      float4 f1 = *(const float4*)(xp + kk * 32 + 4);
      bf16x8 a;
      a[0] = (bf16)f0.x; a[1] = (bf16)f0.y; a[2] = (bf16)f0.z; a[3] = (bf16)f0.w;
      a[4] = (bf16)f1.x; a[5] = (bf16)f1.y; a[6] = (bf16)f1.z; a[7] = (bf16)f1.w;
      A[kk] = a;
    }
    char* sb = (char*)gx + ((size_t)tloc * 64 + bg) * SLAB;
    #pragma unroll
    for (int g = 0; g < 4; ++g) {
      f32x4 acc[3];
      #pragma unroll
      for (int i2 = 0; i2 < 3; ++i2)
        #pragma unroll
        for (int e = 0; e < 4; ++e) acc[i2][e] = bias[g * 3 + i2];
      #pragma unroll
      for (int kk = 0; kk < 8; ++kk)
        #pragma unroll
        for (int i2 = 0; i2 < 3; ++i2)
          acc[i2] = MFMA(A[kk], asb(W[g * 3 + i2][kk]), acc[i2], 0, 0, 0);
      #pragma unroll
      for (int i2 = 0; i2 < 3; ++i2) {
        int ft = w * 12 + g * 3 + i2;
        union { bf16 v[4]; uint2 u; } pk;
        #pragma unroll
        for (int j = 0; j < 4; ++j) pk.v[j] = (bf16)acc[i2][j];
        *(uint2*)(sb + (ft >> 4) * 8192 + (ft & 15) * 512 + loffE) = pk.u;
      }
    }
  }
}

// ============ phase 2: scan; 8 waves x 32 cols; wR/wN pinned in regs, Wc in LDS ============
// 2 waves/SIMD exact (256-reg budget): 128 weight regs + ~100 working.
__global__ __launch_bounds__(512) __attribute__((amdgpu_waves_per_eu(2, 2)))
void k_phase2(
    const bf16* __restrict__ gx, const bf16* __restrict__ whf,
    const bf16* __restrict__ wcf, const float* __restrict__ bh,
    float* __restrict__ out, float* __restrict__ hstate, int t0, int TC) {
  extern __shared__ char lds[];          // [0,131072): Wc frags; [+16384): hb dbuf
  char* hb0 = lds + 131072;
  int tid = threadIdx.x;
  int w = tid >> 6, l = tid & 63, lr = l & 15, lq = l >> 4;
  int bg = blockIdx.x, b0 = bg << 4;
  int loffE = lq * 128 + lr * 8;

  // stage Wc into LDS (frag-major already: contiguous 1KB frags, conflict-free reads)
  #pragma unroll 4
  for (int it = 0; it < 16; ++it)
    *(uint4*)(lds + it * 8192 + tid * 16) =
        *(const uint4*)((const char*)wcf + it * 8192 + tid * 16);

  // wR, wN resident + pinned (cannot be rematerialized)
  uint4 wR[2][8], wN[2][8];
  #pragma unroll
  for (int p = 0; p < 2; ++p)
    #pragma unroll
    for (int kk = 0; kk < 8; ++kk) {
      int ct = 2 * w + p;
      wR[p][kk] = *(const uint4*)(whf + (size_t)(ct * 8 + kk) * 512 + loffE);
      wN[p][kk] = *(const uint4*)(whf + (size_t)((16 + ct) * 8 + kk) * 512 + loffE);
      PIN4(wR[p][kk]); PIN4(wN[p][kk]);
    }
  float bN[2];
  bN[0] = bh[512 + (2 * w + 0) * 16 + lr];
  bN[1] = bh[512 + (2 * w + 1) * 16 + lr];

  float h[2][4];
  #pragma unroll
  for (int p = 0; p < 2; ++p) {
    int col = (2 * w + p) * 16 + lr;
    #pragma unroll
    for (int j = 0; j < 4; ++j)
      h[p][j] = (t0 == 0) ? 0.f : hstate[(size_t)(b0 + 4 * lq + j) * Hsz + col];
    int cb = ((col >> 5) << 10) + (((col >> 3) & 3) << 8) + (lq << 6) + ((col & 7) << 1);
    char* hw = hb0 + cb;
    #pragma unroll
    for (int j = 0; j < 4; ++j) *(bf16*)(hw + j * 16) = (bf16)h[p][j];
  }
  __syncthreads();

  const char* gxb = (const char*)gx + (size_t)bg * SLAB;
  const size_t tstride = (size_t)64 * SLAB;
  uint2 gR[2], gN[2], gA[2];
  #pragma unroll
  for (int p = 0; p < 2; ++p) {
    int toff = (2 * w + p) * 512 + loffE;
    gR[p] = *(const uint2*)(gxb + toff);
    gN[p] = *(const uint2*)(gxb + 8192 + toff);
    gA[p] = *(const uint2*)(gxb + 16384 + toff);
  }

  #pragma unroll 1
  for (int t = 0; t < TC; ++t) {
    int cur = t & 1, nxt = cur ^ 1;
    const char* hc = hb0 + cur * 8192 + lq * 256 + lr * 16;
    char* hn = hb0 + nxt * 8192;
    bf16x8 Ah[8];
    #pragma unroll
    for (int kk = 0; kk < 8; ++kk) Ah[kk] = *(const bf16x8*)(hc + kk * 1024);
    bool pf = (t + 1 < TC);
    const char* sl = gxb + (size_t)(t + 1) * tstride;
    f32x4 aR[2], aN[2], aA[2];
    #pragma unroll
    for (int p = 0; p < 2; ++p)
      #pragma unroll
      for (int e = 0; e < 4; ++e) { aR[p][e] = 0.f; aN[p][e] = bN[p]; aA[p][e] = 0.f; }
    #pragma unroll
    for (int kk = 0; kk < 8; ++kk) {
      aR[0] = MFMA(Ah[kk], asb(wR[0][kk]), aR[0], 0, 0, 0);
      aR[1] = MFMA(Ah[kk], asb(wR[1][kk]), aR[1], 0, 0, 0);
      aN[0] = MFMA(Ah[kk], asb(wN[0][kk]), aN[0], 0, 0, 0);
      aN[1] = MFMA(Ah[kk], asb(wN[1][kk]), aN[1], 0, 0, 0);
      bf16x8 wc0 = *(const bf16x8*)(lds + (size_t)((2 * w + 0) * 8 + kk) * 1024 + lq * 256 + lr * 16);
      aA[0] = MFMA(Ah[kk], wc0, aA[0], 0, 0, 0);
      bf16x8 wc1 = *(const bf16x8*)(lds + (size_t)((2 * w + 1) * 8 + kk) * 1024 + lq * 256 + lr * 16);
      aA[1] = MFMA(Ah[kk], wc1, aA[1], 0, 0, 0);
    }
    #pragma unroll
    for (int p = 0; p < 2; ++p) {
      float irj[4] = { bflo(gR[p].x), bfhi(gR[p].x), bflo(gR[p].y), bfhi(gR[p].y) };
      float inj[4] = { bflo(gN[p].x), bfhi(gN[p].x), bflo(gN[p].y), bfhi(gN[p].y) };
      float aij[4] = { bflo(gA[p].x), bfhi(gA[p].x), bflo(gA[p].y), bfhi(gA[p].y) };
      int col = (2 * w + p) * 16 + lr;
      #pragma unroll
      for (int j = 0; j < 4; ++j) {
        float rg = sigm(irj[j] + aR[p][j]);
        float xx = inj[j] + rg * aN[p][j];
        xx = fminf(fmaxf(xx, -15.f), 15.f);
        float e2 = exp2f(-2.885390081777927f * xx);
        float ng = (1.f - e2) * __builtin_amdgcn_rcpf(1.f + e2);
        float ig = sigm(aij[j] + aA[p][j]);
        h[p][j] = ng + ig * (h[p][j] - ng);
      }
      int cb = ((col >> 5) << 10) + (((col >> 3) & 3) << 8) + (lq << 6) + ((col & 7) << 1);
      char* hw = hn + cb;
      #pragma unroll
      for (int j = 0; j < 4; ++j) *(bf16*)(hw + j * 16) = (bf16)h[p][j];
      #pragma unroll
      for (int j = 0; j < 4; ++j)
        out[(size_t)(b0 + 4 * lq + j) * (Tsz * Hsz) + (size_t)(t0 + t) * Hsz + col] = h[p][j];
      if (pf) {   // next step's gx into same regs (WAR after gate reads)
        int toff = (2 * w + p) * 512 + loffE;
        gR[p] = *(const uint2*)(sl + toff);
        gN[p] = *(const uint2*)(sl + 8192 + toff);
        gA[p] = *(const uint2*)(sl + 16384 + toff);
      }
    }
    asm volatile("s_waitcnt lgkmcnt(0)" ::: "memory");
    __builtin_amdgcn_s_barrier();
    __builtin_amdgcn_sched_barrier(0);
  }
  #pragma unroll
  for (int p = 0; p < 2; ++p) {
    int col = (2 * w + p) * 16 + lr;
    #pragma unroll
    for (int j = 0; j < 4; ++j)
      hstate[(size_t)(b0 + 4 * lq + j) * Hsz + col] = h[p][j];
  }
}

extern "C" void kernel_launch(void* const* d_in, const int* in_sizes, int n_in,
                              void* d_out, int out_size, void* d_ws, size_t ws_size,
                              hipStream_t stream) {
  (void)in_sizes; (void)n_in; (void)out_size;
  const float* x  = (const float*)d_in[0];
  const float* Wx = (const float*)d_in[1];
  const float* bx = (const float*)d_in[2];
  const float* Wh = (const float*)d_in[3];
  const float* bh = (const float*)d_in[4];
  const float* Wa = (const float*)d_in[5];
  const float* ba = (const float*)d_in[6];
  float* out = (float*)d_out;
  char* ws = (char*)d_ws;

  bf16* wxf = (bf16*)ws;                        // 48 tiles * 8KB = 393216 B (R,N,Wp)
  bf16* whf = (bf16*)(ws + 393216);             // 262144 B (R tiles 0..15, N tiles 16..31)
  bf16* wcf = (bf16*)(ws + 655360);             // 131072 B
  float* c0 = (float*)(ws + 786432);            // 1024 B
  float* hstate = (float*)(ws + 1048576);       // 1 MB
  bf16* gxbuf = (bf16*)(ws + 2097152);

  size_t avail = (ws_size > 2097152) ? ws_size - 2097152 : 0;
  size_t per_t = (size_t)64 * SLAB;             // 1.5 MB per timestep
  long tcl = (long)(avail / per_t);
  int TC = (tcl > Tsz) ? Tsz : (int)tcl;
  TC &= ~63;
  if (TC < 64) TC = 64;

  (void)hipFuncSetAttribute((const void*)k_phase2,
                            hipFuncAttributeMaxDynamicSharedMemorySize, 147456);

  k_repack<<<dim3(128), dim3(256), 0, stream>>>(Wx, Wh, wxf, whf);
  k_wc<<<dim3(256), dim3(256), 0, stream>>>(Wa, Wh, Wx, bh, bx, ba, wcf, wxf, c0);
  for (int t0 = 0; t0 < Tsz; t0 += TC) {
    int tc = Tsz - t0; if (tc > TC) tc = TC;
    int TP = tc / 4;                            // grid-y = 4 -> 256 blocks, full chip
    k_phase1<<<dim3(64, 4), dim3(256), 0, stream>>>(x, wxf, bx, bh, c0, gxbuf, t0, TP);
    k_phase2<<<dim3(64), dim3(512), 147456, stream>>>(gxbuf, whf, wcf, bh, out, hstate, t0, tc);
  }
}